// Round 19
// baseline (265.091 us; speedup 1.0000x reference)
//
#include <hip/hip_runtime.h>
#include <hip/hip_bf16.h>
#include <cstdint>
#include <cstddef>

#define B_ 2
#define T_ 2048
#define H_ 32
#define KVH_ 8
#define D_ 64
#define C_ 2048
#define NQKV 3072

typedef short short8 __attribute__((ext_vector_type(8)));
typedef float f32x4 __attribute__((ext_vector_type(4)));
typedef unsigned short u16;

__device__ __forceinline__ u16 f2b(float f) {
  union { float f; unsigned u; } x; x.f = f;
  unsigned r = x.u + 0x7fffu + ((x.u >> 16) & 1u);
  return (u16)(r >> 16);
}

__device__ __forceinline__ void gload16(const void* g, void* l) {
  __builtin_amdgcn_global_load_lds(
      (const __attribute__((address_space(1))) unsigned int*)g,
      (__attribute__((address_space(3))) unsigned int*)l,
      16, 0, 0);
}

__device__ __forceinline__ f32x4 mfma16(short8 a, short8 b, f32x4 c) {
  return __builtin_amdgcn_mfma_f32_16x16x32_bf16(a, b, c, 0, 0, 0);
}

__device__ __forceinline__ unsigned cvtpk(float lo_, float hi_) {
  unsigned r;
  asm("v_cvt_pk_bf16_f32 %0, %1, %2" : "=v"(r) : "v"(lo_), "v"(hi_));
  return r;
}

// ---------------- cos/sin table [T][32] of float2 ----------------
__global__ void k_tbl(float* __restrict__ tbl) {
  int i = blockIdx.x * 256 + threadIdx.x;   // 65536
  int t = i >> 5, f = i & 31;
  double freq = pow(10000.0, -(double)f / 32.0);
  double th = (double)t * freq;
  tbl[i * 2 + 0] = (float)cos(th);
  tbl[i * 2 + 1] = (float)sin(th);
}

// ---------------- x f32 -> bf16 ----------------
__global__ void k_cvtx(const float* __restrict__ x, u16* __restrict__ xb) {
  int i = blockIdx.x * 256 + threadIdx.x;   // one float4 each
  float4 v = ((const float4*)x)[i];
  ushort4 o;
  o.x = f2b(v.x); o.y = f2b(v.y); o.z = f2b(v.z); o.w = f2b(v.w);
  ((ushort4*)xb)[i] = o;
}

// ---------------- merged QKV weight transpose+convert ----------------
__global__ void k_transw_qkv(const float* __restrict__ wq, const float* __restrict__ wk,
                             const float* __restrict__ wv, u16* __restrict__ dst) {
  __shared__ float t[32][33];
  int tx = threadIdx.x, ty = threadIdx.y;       // 32 x 8
  int k0 = blockIdx.y * 32, n0g = blockIdx.x * 32;
  const float* src;
  int N, col0;
  if (n0g < 2048)      { src = wq; N = 2048; col0 = n0g; }
  else if (n0g < 2560) { src = wk; N = 512;  col0 = n0g - 2048; }
  else                 { src = wv; N = 512;  col0 = n0g - 2560; }
#pragma unroll
  for (int i = 0; i < 4; i++)
    t[ty + i * 8][tx] = src[(size_t)(k0 + ty + i * 8) * N + col0 + tx];
  __syncthreads();
#pragma unroll
  for (int i = 0; i < 4; i++) {
    int nl = ty + i * 8;
    dst[(size_t)(n0g + nl) * 2048 + k0 + tx] = f2b(t[tx][nl]);
  }
}

// ---------------- weight transpose+convert: src f32 [K=2048][N] -> dst bf16 [N][2048] ----------------
__global__ void k_transw(const float* __restrict__ src, u16* __restrict__ dst, int N) {
  __shared__ float t[32][33];
  int tx = threadIdx.x, ty = threadIdx.y;       // 32 x 8
  int k0 = blockIdx.y * 32, n0 = blockIdx.x * 32;
#pragma unroll
  for (int i = 0; i < 4; i++)
    t[ty + i * 8][tx] = src[(size_t)(k0 + ty + i * 8) * N + n0 + tx];
  __syncthreads();
#pragma unroll
  for (int i = 0; i < 4; i++) {
    int nl = ty + i * 8;
    dst[(size_t)(n0 + nl) * 2048 + k0 + tx] = f2b(t[tx][nl]);
  }
}

// ---------------- GEMM: 128x128 tile, BK=64 ----------------
// MODE 0: C[M,N] f32 (out-projection).
// MODE 1: fused QKV epilogue (RoPE from f32 acc, head-major Q/K, V transposed).
template <int MODE>
__global__ __launch_bounds__(256, 2) void k_gemm(const u16* __restrict__ A,
                                                 const u16* __restrict__ Bt,
                                                 void* __restrict__ Cc,
                                                 int M, int N, int K,
                                                 const float* __restrict__ tbl,
                                                 u16* __restrict__ Qb,
                                                 u16* __restrict__ Kb,
                                                 u16* __restrict__ Vt) {
  __shared__ __align__(16) u16 As[128 * 64];
  __shared__ __align__(16) u16 Bs[128 * 64];
  const int tid = threadIdx.x;
  const int w = tid >> 6, l = tid & 63;
  const int lo = l & 15, hi = l >> 4;
  const int m0 = blockIdx.y * 128, n0 = blockIdx.x * 128;
  const int wr = w >> 1, wc = w & 1;
  f32x4 acc[4][4];
#pragma unroll
  for (int i = 0; i < 4; i++)
#pragma unroll
    for (int j = 0; j < 4; j++) acc[i][j] = (f32x4){0.f, 0.f, 0.f, 0.f};

  for (int k0 = 0; k0 < K; k0 += 64) {
#pragma unroll
    for (int i = 0; i < 4; i++) {
      int cid = i * 256 + tid;
      int row = cid >> 3, kc = cid & 7;     // 8 chunks of 16B per 64-col row
      gload16(A + (size_t)(m0 + row) * K + k0 + kc * 8, &As[(i * 256 + w * 64) * 8]);
      gload16(Bt + (size_t)(n0 + row) * K + k0 + kc * 8, &Bs[(i * 256 + w * 64) * 8]);
    }
    __syncthreads();
#pragma unroll
    for (int kk = 0; kk < 2; kk++) {
      short8 a[4], b[4];
#pragma unroll
      for (int i = 0; i < 4; i++)
        a[i] = *(const short8*)&As[(wr * 64 + i * 16 + lo) * 64 + kk * 32 + hi * 8];
#pragma unroll
      for (int j = 0; j < 4; j++)
        b[j] = *(const short8*)&Bs[(wc * 64 + j * 16 + lo) * 64 + kk * 32 + hi * 8];
#pragma unroll
      for (int i = 0; i < 4; i++)
#pragma unroll
        for (int j = 0; j < 4; j++) acc[i][j] = mfma16(a[i], b[j], acc[i][j]);
    }
    __syncthreads();
  }
  const int r0 = m0 + wr * 64, c0 = n0 + wc * 64;

  if (MODE == 0) {
#pragma unroll
    for (int i = 0; i < 4; i++)
#pragma unroll
      for (int j = 0; j < 4; j++) {
        f32x4 v = acc[i][j];
        int col = c0 + j * 16 + lo;
        int rw = r0 + i * 16 + hi * 4;
#pragma unroll
        for (int r = 0; r < 4; r++)
          ((float*)Cc)[(size_t)(rw + r) * N + col] = v[r];
      }
  } else {
    const int hd = c0 >> 6;                 // head-block 0..47 (Q 0-31, K 32-39, V 40-47)
    const int b = m0 >> 11;                 // batch (block never straddles T boundary)
    if (hd < 40) {
      const bool isQ = (hd < 32);
      const float sc = isQ ? 0.125f * 1.44269504089f : 1.0f;
      u16* dst = isQ ? (Qb + (size_t)(b * H_ + hd) * T_ * 64)
                     : (Kb + (size_t)(b * KVH_ + (hd - 32)) * T_ * 64);
#pragma unroll
      for (int i = 0; i < 4; i++)
#pragma unroll
        for (int r = 0; r < 4; r++) {
          int t = (r0 + i * 16 + hi * 4 + r) & (T_ - 1);
          float2 cA = *(const float2*)&tbl[((size_t)t * 32 + lo) * 2];
          float2 cB = *(const float2*)&tbl[((size_t)t * 32 + 16 + lo) * 2];
          float a0 = acc[i][0][r], a1 = acc[i][1][r];
          float a2 = acc[i][2][r], a3 = acc[i][3][r];
          size_t rb = (size_t)t * 64;
          dst[rb + lo]      = f2b((a0 * cA.x - a2 * cA.y) * sc);
          dst[rb + 32 + lo] = f2b((a2 * cA.x + a0 * cA.y) * sc);
          dst[rb + 16 + lo] = f2b((a1 * cB.x - a3 * cB.y) * sc);
          dst[rb + 48 + lo] = f2b((a3 * cB.x + a1 * cB.y) * sc);
        }
    } else {
      const int kvh = hd - 40;
      u16* dst = Vt + (size_t)(b * KVH_ + kvh) * 64 * T_;
#pragma unroll
      for (int i = 0; i < 4; i++)
#pragma unroll
        for (int j = 0; j < 4; j++) {
          int t = (r0 + i * 16 + hi * 4) & (T_ - 1);
          int dd = j * 16 + lo;
          f32x4 v = acc[i][j];
          ushort4 ov;
          ov.x = f2b(v[0]); ov.y = f2b(v[1]); ov.z = f2b(v[2]); ov.w = f2b(v[3]);
          *(ushort4*)&dst[(size_t)dd * T_ + t] = ov;    // V transposed: [d][t]
        }
    }
  }
}

// ---------------- Flash attention (causal, GQA), kv-split 4-wave blocks ----------------
// r13 STEP chain VERBATIM (shuffle max+sum softmax, base-2 domain, defer-max 11.5,
// cvt_pk P-pack, K ping-pong, (3,3) no-spill). Structure: one 32-row q-tile per
// 4-wave block; waves split the tile's kv range into quarters (r4's correctness-
// proven design -- it only failed then from the VGPR-64 spill, now fixed).
// 4096 blocks, 3/CU resident -> 3 waves/SIMD (vs 2 at r13's 512-block grid).
// Grid (bh, tile-descending) = global LPT. Combine = r4's LDS-aliased 3-barrier tree.
#define PSTR 40
__global__ __launch_bounds__(256)
__attribute__((amdgpu_waves_per_eu(3, 3)))
void k_attn(const u16* __restrict__ Qb,
            const u16* __restrict__ Kb,
            const u16* __restrict__ Vt,
            u16* __restrict__ Ob) {
  // LDS: [0,10240) per-wave P-buffers during steps; [0,16384) combine O staging
  // after; [16384,17408) m/l exchange. P and O regions alias (barrier-separated).
  __shared__ __align__(16) char lds[17408];
  u16* Pl = (u16*)lds;                       // [(w*2+qt)*16 + lo][PSTR]
  f32x4* cbO0 = (f32x4*)lds;                 // [qt*4+jd][64]
  f32x4* cbO1 = (f32x4*)(lds + 8192);
  float* cbM = (float*)(lds + 16384);        // [(w*2+qt)*16 + lo]
  float* cbL = cbM + 128;

  const int tid = threadIdx.x, w = tid >> 6, l = tid & 63;
  const int lo = l & 15, hi = l >> 4;
  const int bh = blockIdx.x;
  const int b = bh >> 5, h = bh & 31, kvh = h >> 2;
  const int tile = 63 - (int)blockIdx.y;     // descending: all longest blocks first
  const int q0 = tile * 32;
  const int nblk = tile + 1;                 // 32-kv blocks in causal range
  const int s0 = (nblk * w) >> 2;            // this wave's kv-block range
  const int s1 = (nblk * (w + 1)) >> 2;

  const size_t qbase = (size_t)(b * H_ + h) * T_ * 64;
  const size_t kbase = (size_t)(b * KVH_ + kvh) * T_ * 64;
  const size_t vbase = (size_t)(b * KVH_ + kvh) * 64 * T_;

  // Q fragments (B-operand for S^T): lane holds Q[q0+qt*16+lo][hf*32+hi*8 ..+8)
  short8 aq[2][2];
#pragma unroll
  for (int qt = 0; qt < 2; qt++)
#pragma unroll
    for (int hf = 0; hf < 2; hf++)
      aq[qt][hf] = *(const short8*)&Qb[qbase + (size_t)(q0 + qt * 16 + lo) * 64 + hf * 32 + hi * 8];

  f32x4 o[2][4];
  float m[2], lsum[2];
#pragma unroll
  for (int qt = 0; qt < 2; qt++) {
    m[qt] = -1e30f; lsum[qt] = 0.f;
#pragma unroll
    for (int jd = 0; jd < 4; jd++) o[qt][jd] = (f32x4){0.f, 0.f, 0.f, 0.f};
  }

  auto LOADK = [&](short8 (&ak)[2][2], int kv0) {
#pragma unroll
    for (int f = 0; f < 2; f++)
#pragma unroll
      for (int hf = 0; hf < 2; hf++)
        ak[f][hf] = *(const short8*)&Kb[kbase + (size_t)(kv0 + f * 16 + lo) * 64 + hf * 32 + hi * 8];
  };

  auto STEP = [&](const short8 (&ak)[2][2], int kv0, bool masked) {
    // V^T fragments (A-operand for PV): lane holds V^T[jd*16+lo][kv0+hi*8 ..)
    short8 av[4];
#pragma unroll
    for (int jd = 0; jd < 4; jd++)
      av[jd] = *(const short8*)&Vt[vbase + (size_t)(jd * 16 + lo) * T_ + kv0 + hi * 8];

    // S^T[kv][q]: lane holds kv = kv0+f*16+hi*4+r, q = q0+qt*16+lo  (log2 domain)
    f32x4 s[2][2];
    __builtin_amdgcn_s_setprio(1);
#pragma unroll
    for (int qt = 0; qt < 2; qt++)
#pragma unroll
      for (int f = 0; f < 2; f++) {
        f32x4 acc = (f32x4){0.f, 0.f, 0.f, 0.f};
        acc = mfma16(ak[f][0], aq[qt][0], acc);
        acc = mfma16(ak[f][1], aq[qt][1], acc);
        s[qt][f] = acc;
      }
    __builtin_amdgcn_s_setprio(0);

#pragma unroll
    for (int qt = 0; qt < 2; qt++) {
      const int myq = q0 + qt * 16 + lo;
      float p_[8];
#pragma unroll
      for (int f = 0; f < 2; f++)
#pragma unroll
        for (int r = 0; r < 4; r++) {
          float v = s[qt][f][r];
          if (masked) {
            int kv = kv0 + f * 16 + hi * 4 + r;
            v = (kv <= myq) ? v : -1e30f;
          }
          p_[f * 4 + r] = v;
        }
      float mx = fmaxf(fmaxf(fmaxf(p_[0], p_[1]), fmaxf(p_[2], p_[3])),
                       fmaxf(fmaxf(p_[4], p_[5]), fmaxf(p_[6], p_[7])));
      mx = fmaxf(mx, __shfl_xor(mx, 16));
      mx = fmaxf(mx, __shfl_xor(mx, 32));
      if (!__all(mx <= m[qt] + 11.5f)) {    // defer-max: rescale only on big growth
        float mn = fmaxf(m[qt], mx);
        float a_ = exp2f(m[qt] - mn);
        m[qt] = mn;
        lsum[qt] *= a_;
#pragma unroll
        for (int jd = 0; jd < 4; jd++) {
          f32x4 t = o[qt][jd];
#pragma unroll
          for (int r = 0; r < 4; r++) t[r] *= a_;
          o[qt][jd] = t;
        }
      }
      float sm = 0.f;
#pragma unroll
      for (int i = 0; i < 8; i++) { p_[i] = exp2f(p_[i] - m[qt]); sm += p_[i]; }
      sm += __shfl_xor(sm, 16);
      sm += __shfl_xor(sm, 32);
      lsum[qt] += sm;
      // pack P -> LDS [q=lo][kv] via cvt_pk
      uint2 w0, w1;
      w0.x = cvtpk(p_[0], p_[1]); w0.y = cvtpk(p_[2], p_[3]);
      w1.x = cvtpk(p_[4], p_[5]); w1.y = cvtpk(p_[6], p_[7]);
      *(uint2*)&Pl[((w * 2 + qt) * 16 + lo) * PSTR + hi * 4] = w0;
      *(uint2*)&Pl[((w * 2 + qt) * 16 + lo) * PSTR + 16 + hi * 4] = w1;
    }

    // PV: O^T[d][q] += V^T * P ; B-frag = P row q=lo, kv=hi*8..
#pragma unroll
    for (int qt = 0; qt < 2; qt++) {
      short8 pb = *(const short8*)&Pl[((w * 2 + qt) * 16 + lo) * PSTR + hi * 8];
      __builtin_amdgcn_s_setprio(1);
#pragma unroll
      for (int jd = 0; jd < 4; jd++) o[qt][jd] = mfma16(av[jd], pb, o[qt][jd]);
      __builtin_amdgcn_s_setprio(0);
    }
  };

  // per-wave kv loop over [s0, s1), K frags prefetched one block ahead (ping-pong)
  if (s0 < s1) {
    short8 akA[2][2], akB[2][2];
    int kb = s0;
    LOADK(akA, kb * 32);
    while (kb + 2 <= s1) {
      LOADK(akB, (kb + 1) * 32);
      STEP(akA, kb * 32, false);
      if (kb + 2 < s1) LOADK(akA, (kb + 2) * 32);
      STEP(akB, (kb + 1) * 32, (kb + 1) == nblk - 1);
      kb += 2;
    }
    if (kb < s1) STEP(akA, kb * 32, kb == nblk - 1);
  }

  // ---- combine partials across the 4 waves (r4's proven tree) ----
  if (hi == 0) {
#pragma unroll
    for (int qt = 0; qt < 2; qt++) {
      cbM[(w * 2 + qt) * 16 + lo] = m[qt];
      cbL[(w * 2 + qt) * 16 + lo] = lsum[qt];
    }
  }
  __syncthreads();
  float linv[2];
#pragma unroll
  for (int qt = 0; qt < 2; qt++) {
    float m0 = cbM[(0 + qt) * 16 + lo], m1 = cbM[(2 + qt) * 16 + lo],
          m2 = cbM[(4 + qt) * 16 + lo], m3 = cbM[(6 + qt) * 16 + lo];
    float ms = fmaxf(fmaxf(m0, m1), fmaxf(m2, m3));
    float lt = cbL[(0 + qt) * 16 + lo] * exp2f(m0 - ms) +
               cbL[(2 + qt) * 16 + lo] * exp2f(m1 - ms) +
               cbL[(4 + qt) * 16 + lo] * exp2f(m2 - ms) +
               cbL[(6 + qt) * 16 + lo] * exp2f(m3 - ms);
    float sw = exp2f(m[qt] - ms);
    linv[qt] = 1.0f / lt;
#pragma unroll
    for (int jd = 0; jd < 4; jd++) {
      f32x4 t = o[qt][jd];
#pragma unroll
      for (int r = 0; r < 4; r++) t[r] *= sw;
      o[qt][jd] = t;
    }
  }
  if (w == 1) {
#pragma unroll
    for (int qt = 0; qt < 2; qt++)
#pragma unroll
      for (int jd = 0; jd < 4; jd++) cbO0[(qt * 4 + jd) * 64 + l] = o[qt][jd];
  }
  if (w == 3) {
#pragma unroll
    for (int qt = 0; qt < 2; qt++)
#pragma unroll
      for (int jd = 0; jd < 4; jd++) cbO1[(qt * 4 + jd) * 64 + l] = o[qt][jd];
  }
  __syncthreads();
  if (w == 0) {
#pragma unroll
    for (int qt = 0; qt < 2; qt++)
#pragma unroll
      for (int jd = 0; jd < 4; jd++) o[qt][jd] += cbO0[(qt * 4 + jd) * 64 + l];
  }
  if (w == 2) {
#pragma unroll
    for (int qt = 0; qt < 2; qt++)
#pragma unroll
      for (int jd = 0; jd < 4; jd++) o[qt][jd] += cbO1[(qt * 4 + jd) * 64 + l];
  }
  __syncthreads();
  if (w == 2) {
#pragma unroll
    for (int qt = 0; qt < 2; qt++)
#pragma unroll
      for (int jd = 0; jd < 4; jd++) cbO0[(qt * 4 + jd) * 64 + l] = o[qt][jd];
  }
  __syncthreads();
  if (w == 0) {
#pragma unroll
    for (int qt = 0; qt < 2; qt++) {
      const int myq = q0 + qt * 16 + lo;
      size_t obase = ((size_t)(b * T_ + myq) * H_ + h) * 64;
#pragma unroll
      for (int jd = 0; jd < 4; jd++) {
        f32x4 t = o[qt][jd];
        t += cbO0[(qt * 4 + jd) * 64 + l];
        ushort4 ov;
        ov.x = f2b(t[0] * linv[qt]);
        ov.y = f2b(t[1] * linv[qt]);
        ov.z = f2b(t[2] * linv[qt]);
        ov.w = f2b(t[3] * linv[qt]);
        *(ushort4*)&Ob[obase + jd * 16 + hi * 4] = ov;
      }
    }
  }
}

// ---------------- workspace layout ----------------
constexpr size_t OFF_TBL = 0;
constexpr size_t SZ_TBL = (size_t)T_ * 32 * 2 * 4;
constexpr size_t OFF_XB = OFF_TBL + SZ_TBL;
constexpr size_t SZ_XB = (size_t)B_ * T_ * C_ * 2;
constexpr size_t OFF_WQKVT = OFF_XB + SZ_XB;
constexpr size_t SZ_WQKVT = (size_t)NQKV * C_ * 2;
constexpr size_t OFF_WOT = OFF_WQKVT + SZ_WQKVT;
constexpr size_t SZ_WOT = (size_t)C_ * C_ * 2;
constexpr size_t OFF_QB = OFF_WOT + SZ_WOT;
constexpr size_t SZ_QB = (size_t)B_ * H_ * T_ * D_ * 2;
constexpr size_t OFF_KB = OFF_QB + SZ_QB;
constexpr size_t SZ_KVB = (size_t)B_ * KVH_ * T_ * D_ * 2;
constexpr size_t OFF_VT = OFF_KB + SZ_KVB;
constexpr size_t OFF_OB = OFF_VT + SZ_KVB;
constexpr size_t SZ_OB = (size_t)B_ * T_ * H_ * D_ * 2;

extern "C" void kernel_launch(void* const* d_in, const int* in_sizes, int n_in,
                              void* d_out, int out_size, void* d_ws, size_t ws_size,
                              hipStream_t stream) {
  const float* x = (const float*)d_in[0];
  const float* wq = (const float*)d_in[1];
  const float* wk = (const float*)d_in[2];
  const float* wv = (const float*)d_in[3];
  const float* wo = (const float*)d_in[4];

  char* ws = (char*)d_ws;
  float* tbl = (float*)(ws + OFF_TBL);
  u16* xb = (u16*)(ws + OFF_XB);
  u16* wqkvT = (u16*)(ws + OFF_WQKVT);
  u16* woT = (u16*)(ws + OFF_WOT);
  u16* Qb = (u16*)(ws + OFF_QB);
  u16* Kb = (u16*)(ws + OFF_KB);
  u16* Vt = (u16*)(ws + OFF_VT);
  u16* Ob = (u16*)(ws + OFF_OB);

  k_tbl<<<256, 256, 0, stream>>>(tbl);
  k_cvtx<<<8192, 256, 0, stream>>>(x, xb);
  dim3 tb(32, 8);
  k_transw_qkv<<<dim3(96, 64), tb, 0, stream>>>(wq, wk, wv, wqkvT);
  k_transw<<<dim3(64, 64), tb, 0, stream>>>(wo, woT, 2048);

  // GEMM1 with fused RoPE + head-major scatter + V-transpose
  k_gemm<1><<<dim3(NQKV / 128, (B_ * T_) / 128), 256, 0, stream>>>(
      xb, wqkvT, nullptr, B_ * T_, NQKV, C_, tbl, Qb, Kb, Vt);
  k_attn<<<dim3(64, 64), 256, 0, stream>>>(Qb, Kb, Vt, Ob);
  k_gemm<0><<<dim3(C_ / 128, (B_ * T_) / 128), 256, 0, stream>>>(
      Ob, woT, d_out, B_ * T_, C_, C_, nullptr, nullptr, nullptr, nullptr);
}

// Round 20
// 255.966 us; speedup vs baseline: 1.0356x; 1.0356x over previous
//
#include <hip/hip_runtime.h>
#include <hip/hip_bf16.h>
#include <cstdint>
#include <cstddef>

#define B_ 2
#define T_ 2048
#define H_ 32
#define KVH_ 8
#define D_ 64
#define C_ 2048
#define NQKV 3072

typedef short short8 __attribute__((ext_vector_type(8)));
typedef float f32x4 __attribute__((ext_vector_type(4)));
typedef unsigned short u16;

__device__ __forceinline__ u16 f2b(float f) {
  union { float f; unsigned u; } x; x.f = f;
  unsigned r = x.u + 0x7fffu + ((x.u >> 16) & 1u);
  return (u16)(r >> 16);
}

__device__ __forceinline__ void gload16(const void* g, void* l) {
  __builtin_amdgcn_global_load_lds(
      (const __attribute__((address_space(1))) unsigned int*)g,
      (__attribute__((address_space(3))) unsigned int*)l,
      16, 0, 0);
}

__device__ __forceinline__ f32x4 mfma16(short8 a, short8 b, f32x4 c) {
  return __builtin_amdgcn_mfma_f32_16x16x32_bf16(a, b, c, 0, 0, 0);
}

__device__ __forceinline__ unsigned cvtpk(float lo_, float hi_) {
  unsigned r;
  asm("v_cvt_pk_bf16_f32 %0, %1, %2" : "=v"(r) : "v"(lo_), "v"(hi_));
  return r;
}

// ---------------- x f32 -> bf16 ; blocks 0..255 also build the cos/sin table ----------------
__global__ void k_cvtx(const float* __restrict__ x, u16* __restrict__ xb,
                       float* __restrict__ tbl) {
  int i = blockIdx.x * 256 + threadIdx.x;   // one float4 each
  float4 v = ((const float4*)x)[i];
  ushort4 o;
  o.x = f2b(v.x); o.y = f2b(v.y); o.z = f2b(v.z); o.w = f2b(v.w);
  ((ushort4*)xb)[i] = o;
  if (blockIdx.x < 256) {                   // tbl: [T][32] of float2 (cos, sin)
    int t = i >> 5, f = i & 31;
    double freq = pow(10000.0, -(double)f / 32.0);
    double th = (double)t * freq;
    tbl[i * 2 + 0] = (float)cos(th);
    tbl[i * 2 + 1] = (float)sin(th);
  }
}

// ---------------- merged QKV weight transpose+convert ----------------
// dst bf16 [3072][2048]; col block selects source: wq (0..2047, N=2048),
// wk (2048..2559, N=512), wv (2560..3071, N=512); 32-col blocks never straddle.
__global__ void k_transw_qkv(const float* __restrict__ wq, const float* __restrict__ wk,
                             const float* __restrict__ wv, u16* __restrict__ dst) {
  __shared__ float t[32][33];
  int tx = threadIdx.x, ty = threadIdx.y;       // 32 x 8
  int k0 = blockIdx.y * 32, n0g = blockIdx.x * 32;
  const float* src;
  int N, col0;
  if (n0g < 2048)      { src = wq; N = 2048; col0 = n0g; }
  else if (n0g < 2560) { src = wk; N = 512;  col0 = n0g - 2048; }
  else                 { src = wv; N = 512;  col0 = n0g - 2560; }
#pragma unroll
  for (int i = 0; i < 4; i++)
    t[ty + i * 8][tx] = src[(size_t)(k0 + ty + i * 8) * N + col0 + tx];
  __syncthreads();
#pragma unroll
  for (int i = 0; i < 4; i++) {
    int nl = ty + i * 8;
    dst[(size_t)(n0g + nl) * 2048 + k0 + tx] = f2b(t[tx][nl]);
  }
}

// ---------------- weight transpose+convert: src f32 [K=2048][N] -> dst bf16 [N][2048] ----------------
__global__ void k_transw(const float* __restrict__ src, u16* __restrict__ dst, int N) {
  __shared__ float t[32][33];
  int tx = threadIdx.x, ty = threadIdx.y;       // 32 x 8
  int k0 = blockIdx.y * 32, n0 = blockIdx.x * 32;
#pragma unroll
  for (int i = 0; i < 4; i++)
    t[ty + i * 8][tx] = src[(size_t)(k0 + ty + i * 8) * N + n0 + tx];
  __syncthreads();
#pragma unroll
  for (int i = 0; i < 4; i++) {
    int nl = ty + i * 8;
    dst[(size_t)(n0 + nl) * 2048 + k0 + tx] = f2b(t[tx][nl]);
  }
}

// ---------------- GEMM: 128x128 tile, BK=64 ----------------
// MODE 0: C[M,N] f32 (out-projection).
// MODE 1: fused QKV epilogue (RoPE from f32 acc, head-major Q/K, V transposed).
template <int MODE>
__global__ __launch_bounds__(256, 2) void k_gemm(const u16* __restrict__ A,
                                                 const u16* __restrict__ Bt,
                                                 void* __restrict__ Cc,
                                                 int M, int N, int K,
                                                 const float* __restrict__ tbl,
                                                 u16* __restrict__ Qb,
                                                 u16* __restrict__ Kb,
                                                 u16* __restrict__ Vt) {
  __shared__ __align__(16) u16 As[128 * 64];
  __shared__ __align__(16) u16 Bs[128 * 64];
  const int tid = threadIdx.x;
  const int w = tid >> 6, l = tid & 63;
  const int lo = l & 15, hi = l >> 4;
  const int m0 = blockIdx.y * 128, n0 = blockIdx.x * 128;
  const int wr = w >> 1, wc = w & 1;
  f32x4 acc[4][4];
#pragma unroll
  for (int i = 0; i < 4; i++)
#pragma unroll
    for (int j = 0; j < 4; j++) acc[i][j] = (f32x4){0.f, 0.f, 0.f, 0.f};

  for (int k0 = 0; k0 < K; k0 += 64) {
#pragma unroll
    for (int i = 0; i < 4; i++) {
      int cid = i * 256 + tid;
      int row = cid >> 3, kc = cid & 7;     // 8 chunks of 16B per 64-col row
      gload16(A + (size_t)(m0 + row) * K + k0 + kc * 8, &As[(i * 256 + w * 64) * 8]);
      gload16(Bt + (size_t)(n0 + row) * K + k0 + kc * 8, &Bs[(i * 256 + w * 64) * 8]);
    }
    __syncthreads();
#pragma unroll
    for (int kk = 0; kk < 2; kk++) {
      short8 a[4], b[4];
#pragma unroll
      for (int i = 0; i < 4; i++)
        a[i] = *(const short8*)&As[(wr * 64 + i * 16 + lo) * 64 + kk * 32 + hi * 8];
#pragma unroll
      for (int j = 0; j < 4; j++)
        b[j] = *(const short8*)&Bs[(wc * 64 + j * 16 + lo) * 64 + kk * 32 + hi * 8];
#pragma unroll
      for (int i = 0; i < 4; i++)
#pragma unroll
        for (int j = 0; j < 4; j++) acc[i][j] = mfma16(a[i], b[j], acc[i][j]);
    }
    __syncthreads();
  }
  const int r0 = m0 + wr * 64, c0 = n0 + wc * 64;

  if (MODE == 0) {
#pragma unroll
    for (int i = 0; i < 4; i++)
#pragma unroll
      for (int j = 0; j < 4; j++) {
        f32x4 v = acc[i][j];
        int col = c0 + j * 16 + lo;
        int rw = r0 + i * 16 + hi * 4;
#pragma unroll
        for (int r = 0; r < 4; r++)
          ((float*)Cc)[(size_t)(rw + r) * N + col] = v[r];
      }
  } else {
    const int hd = c0 >> 6;                 // head-block 0..47 (Q 0-31, K 32-39, V 40-47)
    const int b = m0 >> 11;                 // batch (block never straddles T boundary)
    if (hd < 40) {
      const bool isQ = (hd < 32);
      const float sc = isQ ? 0.125f * 1.44269504089f : 1.0f;
      u16* dst = isQ ? (Qb + (size_t)(b * H_ + hd) * T_ * 64)
                     : (Kb + (size_t)(b * KVH_ + (hd - 32)) * T_ * 64);
#pragma unroll
      for (int i = 0; i < 4; i++)
#pragma unroll
        for (int r = 0; r < 4; r++) {
          int t = (r0 + i * 16 + hi * 4 + r) & (T_ - 1);
          float2 cA = *(const float2*)&tbl[((size_t)t * 32 + lo) * 2];
          float2 cB = *(const float2*)&tbl[((size_t)t * 32 + 16 + lo) * 2];
          float a0 = acc[i][0][r], a1 = acc[i][1][r];
          float a2 = acc[i][2][r], a3 = acc[i][3][r];
          size_t rb = (size_t)t * 64;
          dst[rb + lo]      = f2b((a0 * cA.x - a2 * cA.y) * sc);
          dst[rb + 32 + lo] = f2b((a2 * cA.x + a0 * cA.y) * sc);
          dst[rb + 16 + lo] = f2b((a1 * cB.x - a3 * cB.y) * sc);
          dst[rb + 48 + lo] = f2b((a3 * cB.x + a1 * cB.y) * sc);
        }
    } else {
      const int kvh = hd - 40;
      u16* dst = Vt + (size_t)(b * KVH_ + kvh) * 64 * T_;
#pragma unroll
      for (int i = 0; i < 4; i++)
#pragma unroll
        for (int j = 0; j < 4; j++) {
          int t = (r0 + i * 16 + hi * 4) & (T_ - 1);
          int dd = j * 16 + lo;
          f32x4 v = acc[i][j];
          ushort4 ov;
          ov.x = f2b(v[0]); ov.y = f2b(v[1]); ov.z = f2b(v[2]); ov.w = f2b(v[3]);
          *(ushort4*)&dst[(size_t)dd * T_ + t] = ov;    // V transposed: [d][t]
        }
    }
  }
}

// ---------------- Flash attention (causal, GQA), barrier-free swapped-operand ----------------
// Round-13 verified kernel (140us), VERBATIM: sequential tile-pair per wave (p, 63-p)
// -> every wave exactly 65 steps (makespan within 1.6% of the 64-step lower bound);
// chain = shuffle max+sum softmax in base-2 domain, defer-max 11.5, cvt_pk P-pack
// through per-wave LDS, K ping-pong prefetch, (3,3) no-spill. Survived 7 challenge
// experiments (r11,r12,r14,r15,r17,r19) -- frozen.
#define PSTR 40
__global__ __launch_bounds__(256)
__attribute__((amdgpu_waves_per_eu(3, 3)))
void k_attn(const u16* __restrict__ Qb,
            const u16* __restrict__ Kb,
            const u16* __restrict__ Vt,
            u16* __restrict__ Ob) {
  __shared__ __align__(16) u16 Pl[4][2][16 * PSTR];
  const int tid = threadIdx.x, w = tid >> 6, l = tid & 63;
  const int lo = l & 15, hi = l >> 4;
  const int b = blockIdx.z, h = blockIdx.y, kvh = h >> 2;
  const int p = (int)blockIdx.x * 4 + w;     // pair index 0..31

  const size_t qbase = (size_t)(b * H_ + h) * T_ * 64;
  const size_t kbase = (size_t)(b * KVH_ + kvh) * T_ * 64;
  const size_t vbase = (size_t)(b * KVH_ + kvh) * 64 * T_;

  auto LOADK = [&](short8 (&ak)[2][2], int kv0) {
#pragma unroll
    for (int f = 0; f < 2; f++)
#pragma unroll
      for (int hf = 0; hf < 2; hf++)
        ak[f][hf] = *(const short8*)&Kb[kbase + (size_t)(kv0 + f * 16 + lo) * 64 + hf * 32 + hi * 8];
  };

  for (int pass = 0; pass < 2; pass++) {
    const int tile = pass ? (63 - p) : p;
    const int q0 = tile * 32;

    // Q fragments (B-operand for S^T): lane holds Q[q0+qt*16+lo][hf*32+hi*8 ..+8)
    short8 aq[2][2];
#pragma unroll
    for (int qt = 0; qt < 2; qt++)
#pragma unroll
      for (int hf = 0; hf < 2; hf++)
        aq[qt][hf] = *(const short8*)&Qb[qbase + (size_t)(q0 + qt * 16 + lo) * 64 + hf * 32 + hi * 8];

    f32x4 o[2][4];
    float m[2], lsum[2];
#pragma unroll
    for (int qt = 0; qt < 2; qt++) {
      m[qt] = -1e30f; lsum[qt] = 0.f;
#pragma unroll
      for (int jd = 0; jd < 4; jd++) o[qt][jd] = (f32x4){0.f, 0.f, 0.f, 0.f};
    }

    auto STEP = [&](const short8 (&ak)[2][2], int kv0, bool masked) {
      // V^T fragments (A-operand for PV): lane holds V^T[jd*16+lo][kv0+hi*8 ..)
      short8 av[4];
#pragma unroll
      for (int jd = 0; jd < 4; jd++)
        av[jd] = *(const short8*)&Vt[vbase + (size_t)(jd * 16 + lo) * T_ + kv0 + hi * 8];

      // S^T[kv][q]: lane holds kv = kv0+f*16+hi*4+r, q = q0+qt*16+lo  (log2 domain)
      f32x4 s[2][2];
      __builtin_amdgcn_s_setprio(1);
#pragma unroll
      for (int qt = 0; qt < 2; qt++)
#pragma unroll
        for (int f = 0; f < 2; f++) {
          f32x4 acc = (f32x4){0.f, 0.f, 0.f, 0.f};
          acc = mfma16(ak[f][0], aq[qt][0], acc);
          acc = mfma16(ak[f][1], aq[qt][1], acc);
          s[qt][f] = acc;
        }
      __builtin_amdgcn_s_setprio(0);

#pragma unroll
      for (int qt = 0; qt < 2; qt++) {
        const int myq = q0 + qt * 16 + lo;
        float p_[8];
#pragma unroll
        for (int f = 0; f < 2; f++)
#pragma unroll
          for (int r = 0; r < 4; r++) {
            float v = s[qt][f][r];
            if (masked) {
              int kv = kv0 + f * 16 + hi * 4 + r;
              v = (kv <= myq) ? v : -1e30f;
            }
            p_[f * 4 + r] = v;
          }
        float mx = fmaxf(fmaxf(fmaxf(p_[0], p_[1]), fmaxf(p_[2], p_[3])),
                         fmaxf(fmaxf(p_[4], p_[5]), fmaxf(p_[6], p_[7])));
        mx = fmaxf(mx, __shfl_xor(mx, 16));
        mx = fmaxf(mx, __shfl_xor(mx, 32));
        if (!__all(mx <= m[qt] + 11.5f)) {    // defer-max: rescale only on big growth
          float mn = fmaxf(m[qt], mx);
          float a_ = exp2f(m[qt] - mn);
          m[qt] = mn;
          lsum[qt] *= a_;
#pragma unroll
          for (int jd = 0; jd < 4; jd++) {
            f32x4 t = o[qt][jd];
#pragma unroll
            for (int r = 0; r < 4; r++) t[r] *= a_;
            o[qt][jd] = t;
          }
        }
        float sm = 0.f;
#pragma unroll
        for (int i = 0; i < 8; i++) { p_[i] = exp2f(p_[i] - m[qt]); sm += p_[i]; }
        sm += __shfl_xor(sm, 16);
        sm += __shfl_xor(sm, 32);
        lsum[qt] += sm;
        // pack P -> LDS [q=lo][kv] via cvt_pk (8 ops instead of 16 f2b)
        uint2 w0, w1;
        w0.x = cvtpk(p_[0], p_[1]); w0.y = cvtpk(p_[2], p_[3]);
        w1.x = cvtpk(p_[4], p_[5]); w1.y = cvtpk(p_[6], p_[7]);
        *(uint2*)&Pl[w][qt][lo * PSTR + hi * 4] = w0;
        *(uint2*)&Pl[w][qt][lo * PSTR + 16 + hi * 4] = w1;
      }

      // PV: O^T[d][q] += V^T * P ; B-frag = P row q=lo, kv=hi*8..
#pragma unroll
      for (int qt = 0; qt < 2; qt++) {
        short8 pb = *(const short8*)&Pl[w][qt][lo * PSTR + hi * 8];
        __builtin_amdgcn_s_setprio(1);
#pragma unroll
        for (int jd = 0; jd < 4; jd++) o[qt][jd] = mfma16(av[jd], pb, o[qt][jd]);
        __builtin_amdgcn_s_setprio(0);
      }
    };

    // pair-unrolled pipeline: K frags prefetched one 32-kv block ahead
    short8 akA[2][2], akB[2][2];
    LOADK(akA, 0);
    int kv0 = 0;
    while (kv0 + 64 <= q0) {
      LOADK(akB, kv0 + 32);
      STEP(akA, kv0, false);
      LOADK(akA, kv0 + 64);
      STEP(akB, kv0 + 32, false);
      kv0 += 64;
    }
    if (kv0 < q0) {
      LOADK(akB, q0);
      STEP(akA, kv0, false);
      STEP(akB, q0, true);
    } else {
      STEP(akA, q0, true);
    }

    // epilogue: lane holds O[q][d=jd*16+hi*4+r]
#pragma unroll
    for (int qt = 0; qt < 2; qt++) {
      const int myq = q0 + qt * 16 + lo;
      float inv = 1.0f / lsum[qt];
      size_t obase = ((size_t)(b * T_ + myq) * H_ + h) * 64;
#pragma unroll
      for (int jd = 0; jd < 4; jd++) {
        ushort4 ov;
        ov.x = f2b(o[qt][jd][0] * inv);
        ov.y = f2b(o[qt][jd][1] * inv);
        ov.z = f2b(o[qt][jd][2] * inv);
        ov.w = f2b(o[qt][jd][3] * inv);
        *(ushort4*)&Ob[obase + jd * 16 + hi * 4] = ov;
      }
    }
  }
}

// ---------------- workspace layout ----------------
constexpr size_t OFF_TBL = 0;
constexpr size_t SZ_TBL = (size_t)T_ * 32 * 2 * 4;
constexpr size_t OFF_XB = OFF_TBL + SZ_TBL;
constexpr size_t SZ_XB = (size_t)B_ * T_ * C_ * 2;
constexpr size_t OFF_WQKVT = OFF_XB + SZ_XB;
constexpr size_t SZ_WQKVT = (size_t)NQKV * C_ * 2;
constexpr size_t OFF_WOT = OFF_WQKVT + SZ_WQKVT;
constexpr size_t SZ_WOT = (size_t)C_ * C_ * 2;
constexpr size_t OFF_QB = OFF_WOT + SZ_WOT;
constexpr size_t SZ_QB = (size_t)B_ * H_ * T_ * D_ * 2;
constexpr size_t OFF_KB = OFF_QB + SZ_QB;
constexpr size_t SZ_KVB = (size_t)B_ * KVH_ * T_ * D_ * 2;
constexpr size_t OFF_VT = OFF_KB + SZ_KVB;
constexpr size_t OFF_OB = OFF_VT + SZ_KVB;
constexpr size_t SZ_OB = (size_t)B_ * T_ * H_ * D_ * 2;

extern "C" void kernel_launch(void* const* d_in, const int* in_sizes, int n_in,
                              void* d_out, int out_size, void* d_ws, size_t ws_size,
                              hipStream_t stream) {
  const float* x = (const float*)d_in[0];
  const float* wq = (const float*)d_in[1];
  const float* wk = (const float*)d_in[2];
  const float* wv = (const float*)d_in[3];
  const float* wo = (const float*)d_in[4];

  char* ws = (char*)d_ws;
  float* tbl = (float*)(ws + OFF_TBL);
  u16* xb = (u16*)(ws + OFF_XB);
  u16* wqkvT = (u16*)(ws + OFF_WQKVT);
  u16* woT = (u16*)(ws + OFF_WOT);
  u16* Qb = (u16*)(ws + OFF_QB);
  u16* Kb = (u16*)(ws + OFF_KB);
  u16* Vt = (u16*)(ws + OFF_VT);
  u16* Ob = (u16*)(ws + OFF_OB);

  k_cvtx<<<8192, 256, 0, stream>>>(x, xb, tbl);   // also builds RoPE table
  dim3 tb(32, 8);
  k_transw_qkv<<<dim3(96, 64), tb, 0, stream>>>(wq, wk, wv, wqkvT);
  k_transw<<<dim3(64, 64), tb, 0, stream>>>(wo, woT, 2048);

  // GEMM1 with fused RoPE + head-major scatter + V-transpose
  k_gemm<1><<<dim3(NQKV / 128, (B_ * T_) / 128), 256, 0, stream>>>(
      xb, wqkvT, nullptr, B_ * T_, NQKV, C_, tbl, Qb, Kb, Vt);
  k_attn<<<dim3(8, H_, B_), 256, 0, stream>>>(Qb, Kb, Vt, Ob);
  k_gemm<0><<<dim3(C_ / 128, (B_ * T_) / 128), 256, 0, stream>>>(
      Ob, woT, d_out, B_ * T_, C_, C_, nullptr, nullptr, nullptr, nullptr);
}